// Round 13
// baseline (4585.286 us; speedup 1.0000x reference)
//
#include <hip/hip_runtime.h>

// LSTM char-RNN scan: B=512, SEQ=1024, UNITS=256, NUM_CHARS=128. fp32 in/out.
// Round 12 = r11 winner (4.52 ms: 16 waves, 2REG/1LDS/1STREAM nt per wave,
// bf16 h, LDS token window) + ONE change: parity-buffered A planes so each
// step needs a single __syncthreads (was 2). r12's gather-hoist was neutral
// and is reverted. Rationale: active-CU counters show ~4k cyc/step of
// barrier-drain/convergence; halving barrier count targets exactly that.
// Numerics frozen: W_h bf16 RNE, h bf16 RNE, c/gates fp32 (absmax 4.8828e-4
// in r5-r12).

#define U       256
#define SEQ     1024
#define NC      128
#define GDIM    1024
#define BCR     16         // batch rows per WG
#define THREADS 1024       // 16 waves

typedef short bf16x8 __attribute__((ext_vector_type(8)));
typedef float f32x4  __attribute__((ext_vector_type(4)));

#define WP_OFF   0                        // 512 KB packed W_h
#define WXP_OFF  (512*1024)               // 512 KB packed Wx+bias
#define WS_NEED  (1024*1024)

__device__ __forceinline__ float sig_(float x)  { return 1.0f / (1.0f + __expf(-x)); }
__device__ __forceinline__ float tanh_(float x) { return 1.0f - 2.0f / (__expf(2.0f * x) + 1.0f); }
__device__ __forceinline__ unsigned rne16(float f) {
    union { float f; unsigned u; } v; v.f = f;
    return (v.u + 0x7FFFu + ((v.u >> 16) & 1u)) >> 16;
}
__device__ __forceinline__ float u2f(unsigned u) {
    union { unsigned u; float f; } v; v.u = u; return v.f;
}

// ---- pack W_h into MFMA B-frag order (validated rounds 5-12) ----
// Wp[(nt*8+kt)*64 + lane]: col = nt*16+(lane&15); k = kt*32+(lane>>4)*8 + j,
// dword d packs (k=2d lo, k=2d+1 hi).
__global__ __launch_bounds__(256)
void pack_wh(const float* __restrict__ Wh, uint4* __restrict__ Wp) {
    int i    = blockIdx.x * 256 + threadIdx.x;   // [0, 32768)
    int lane = i & 63;
    int kt   = (i >> 6) & 7;
    int nt   = i >> 9;
    int col  = nt * 16 + (lane & 15);
    int k0   = kt * 32 + ((lane >> 4) * 8);
    const float* base = Wh + (size_t)k0 * GDIM + col;
    unsigned p0 = rne16(base[0 * GDIM]) | (rne16(base[1 * GDIM]) << 16);
    unsigned p1 = rne16(base[2 * GDIM]) | (rne16(base[3 * GDIM]) << 16);
    unsigned p2 = rne16(base[4 * GDIM]) | (rne16(base[5 * GDIM]) << 16);
    unsigned p3 = rne16(base[6 * GDIM]) | (rne16(base[7 * GDIM]) << 16);
    Wp[i] = make_uint4(p0, p1, p2, p3);
}

// ---- pack Wx + bias (+forget_bias) into float4 per (x, unit) ----
__global__ __launch_bounds__(256)
void pack_wx(const float* __restrict__ Wx, const float* __restrict__ bias,
             float4* __restrict__ Wxp) {
    int i = blockIdx.x * 256 + threadIdx.x;      // [0, 32768)
    int x = i >> 8, u = i & 255;
    const float* r = Wx + (size_t)x * GDIM;
    Wxp[i] = make_float4(r[u]       + bias[u],
                         r[256 + u] + bias[256 + u],
                         r[512 + u] + bias[512 + u] + 1.0f,   // forget_bias
                         r[768 + u] + bias[768 + u]);
}

__global__ __launch_bounds__(THREADS, 4)
void lstm_reg16(const int* __restrict__ tokens,
                const uint4* __restrict__ Wp,     // packed W_h (ws)
                const float4* __restrict__ Wxp,   // packed Wx+b (ws)
                const float* __restrict__ Wd,     // [256,128]
                const float* __restrict__ bd,     // [128]
                float* __restrict__ out)          // [512,128]
{
    __shared__ uint4 LW[16][8][64];      // 128 KB  W in LDS (1 nt per wave)
    __shared__ short AH[2][8][64][8];    // 16 KB   h bf16, parity-buffered
    __shared__ int   tokw[64][16];       // 4 KB    64-step token window

    const int tid  = threadIdx.x;
    const int wv   = tid >> 6;        // wave 0..15
    const int lane = tid & 63;
    const int m    = lane & 15;
    const int quad = lane >> 4;
    const int r0   = blockIdx.x * BCR;

    // wave wv owns unit block wv (units wv*16+m); gates i,j,f,o at
    // nt = wv, 16+wv, 32+wv, 48+wv.  REG: {wv, 16+wv}. LDS: {32+wv}.
    // STREAM: {48+wv} (1-deep rolling prefetch, as r11).
    bf16x8 WR[2][8];                  // 64 regs
    #pragma unroll
    for (int jj = 0; jj < 2; ++jj)
        #pragma unroll
        for (int kt = 0; kt < 8; ++kt) {
            union { uint4 u; bf16x8 v; } c;
            c.u = Wp[((size_t)((wv + 16 * jj) * 8 + kt)) * 64 + lane];
            WR[jj][kt] = c.v;
        }
    #pragma unroll
    for (int kt = 0; kt < 8; ++kt)
        LW[wv][kt][lane] = Wp[((size_t)((32 + wv) * 8 + kt)) * 64 + lane];
    for (int i = tid; i < 4096; i += THREADS)    // zero both A parities
        ((int*)AH)[i] = 0;

    float cst[4] = {0.f, 0.f, 0.f, 0.f};
    const int uA = wv * 16 + m;
    const int kt_u = uA >> 5, qa = (uA >> 3) & 3, ju = uA & 7;
    const uint4* sp = Wp + ((size_t)(48 + wv) * 8) * 64 + lane;

    __syncthreads();

    for (int t = 0; t < SEQ; ++t) {
        const int p = t & 1;
        if ((t & 63) == 0) {           // refresh token window
            tokw[tid >> 4][tid & 15] =
                tokens[(size_t)(r0 + (tid & 15)) * SEQ + t + (tid >> 4)];
            __syncthreads();
        }

        // ---- MFMA phase: 4 acc x 8 kt (read parity p) ----
        f32x4 acc[4];
        #pragma unroll
        for (int j = 0; j < 4; ++j) acc[j] = (f32x4){0.f, 0.f, 0.f, 0.f};

        uint4 s = sp[0];
        #pragma unroll
        for (int kt = 0; kt < 8; ++kt) {
            bf16x8 ah = *(const bf16x8*)&AH[p][kt][lane][0];
            uint4 n;
            if (kt < 7) n = sp[(kt + 1) * 64];
            union { uint4 u; bf16x8 v; } l, b;
            l.u = LW[wv][kt][lane];
            b.u = s;
            acc[0] = __builtin_amdgcn_mfma_f32_16x16x32_bf16(ah, WR[0][kt], acc[0], 0, 0, 0);
            acc[1] = __builtin_amdgcn_mfma_f32_16x16x32_bf16(ah, WR[1][kt], acc[1], 0, 0, 0);
            acc[2] = __builtin_amdgcn_mfma_f32_16x16x32_bf16(ah, l.v, acc[2], 0, 0, 0);
            acc[3] = __builtin_amdgcn_mfma_f32_16x16x32_bf16(ah, b.v, acc[3], 0, 0, 0);
            s = n;
        }

        // ---- in-register LSTM update (4 rows per lane, 1 unit) ----
        unsigned hh[4];
        #pragma unroll
        for (int ri = 0; ri < 4; ++ri) {
            const int x = tokw[t & 63][quad * 4 + ri];
            float4 wx = Wxp[(size_t)x * 256 + uA];
            float gi = acc[0][ri] + wx.x;
            float gj = acc[1][ri] + wx.y;
            float gf = acc[2][ri] + wx.z;    // forget_bias folded
            float go = acc[3][ri] + wx.w;
            float c  = cst[ri];
            c = c * sig_(gf) + sig_(gi) * tanh_(gj);
            cst[ri] = c;
            hh[ri] = rne16(tanh_(c) * sig_(go));
        }

        // ---- store h(t) to parity 1-p; SINGLE barrier per step ----
        // (reads(t) of plane p precede this wave's barrier; writes(t+1) to
        //  plane p follow it -> both hazards ordered by one barrier)
        #pragma unroll
        for (int ri = 0; ri < 4; ++ri)
            AH[1 - p][kt_u][qa * 16 + quad * 4 + ri][ju] = (short)hh[ri];
        __syncthreads();
    }

    // ---- final dense (h of t=1023 lives in plane 0) ----
    for (int o = tid; o < BCR * NC; o += THREADS) {
        const int r = o >> 7;
        const int n = o & (NC - 1);
        float sum = bd[n];
        #pragma unroll 4
        for (int k = 0; k < U; ++k) {
            float hk = u2f(((unsigned)(unsigned short)
                            AH[0][k >> 5][((k >> 3) & 3) * 16 + r][k & 7]) << 16);
            sum = fmaf(hk, Wd[k * NC + n], sum);
        }
        out[(size_t)(r0 + r) * NC + n] = sum;
    }
}

// ================= fallback: round-5 streaming kernel (proven 7.6 ms) =========
__global__ __launch_bounds__(256)
void pack_kq(const float* __restrict__ Wh, uint4* __restrict__ Whb) {
    int idx = blockIdx.x * 256 + threadIdx.x;
    int kq  = idx >> 10;
    int c   = idx & 1023;
    const float* base = Wh + (size_t)(kq * 8) * GDIM + c;
    unsigned p0 = rne16(base[0 * GDIM]) | (rne16(base[1 * GDIM]) << 16);
    unsigned p1 = rne16(base[2 * GDIM]) | (rne16(base[3 * GDIM]) << 16);
    unsigned p2 = rne16(base[4 * GDIM]) | (rne16(base[5 * GDIM]) << 16);
    unsigned p3 = rne16(base[6 * GDIM]) | (rne16(base[7 * GDIM]) << 16);
    Whb[idx] = make_uint4(p0, p1, p2, p3);
}

__global__ __launch_bounds__(1024, 4)
void lstm_stream(const int* __restrict__ tokens, const float* __restrict__ Wx,
                 const uint4* __restrict__ Whb, const float* __restrict__ bias,
                 const float* __restrict__ Wd, const float* __restrict__ bd,
                 float* __restrict__ out)
{
    __shared__ float h32[2][U];
    __shared__ float G2[GDIM][2];
    __shared__ int   tok[2][SEQ];
    const int tid = threadIdx.x;
    const int r0  = blockIdx.x * 2;
    for (int i = tid; i < 2 * SEQ; i += 1024)
        ((int*)tok)[i] = tokens[r0 * SEQ + i];
    if (tid < 2 * U) ((float*)h32)[tid] = 0.0f;
    const float b_c = bias[tid];
    float c_state = 0.0f;
    const int ur = tid >> 8, uu = tid & 255;
    __syncthreads();
    const uint4* wp = Whb + tid;
    for (int t = 0; t < SEQ; ++t) {
        const int x0 = tok[0][t], x1 = tok[1][t];
        float a0e = Wx[x0 * GDIM + tid] + b_c;
        float a1e = Wx[x1 * GDIM + tid] + b_c;
        float a0o = 0.f, a1o = 0.f;
        #pragma unroll 4
        for (int kq = 0; kq < 32; ++kq) {
            float4 h0a = *(const float4*)&h32[0][kq * 8];
            float4 h0b = *(const float4*)&h32[0][kq * 8 + 4];
            float4 h1a = *(const float4*)&h32[1][kq * 8];
            float4 h1b = *(const float4*)&h32[1][kq * 8 + 4];
            uint4 wv2 = wp[kq << 10];
            float we0 = u2f(wv2.x << 16), wo0 = u2f(wv2.x & 0xffff0000u);
            float we1 = u2f(wv2.y << 16), wo1 = u2f(wv2.y & 0xffff0000u);
            float we2 = u2f(wv2.z << 16), wo2 = u2f(wv2.z & 0xffff0000u);
            float we3 = u2f(wv2.w << 16), wo3 = u2f(wv2.w & 0xffff0000u);
            a0e = fmaf(h0a.x, we0, a0e); a0o = fmaf(h0a.y, wo0, a0o);
            a1e = fmaf(h1a.x, we0, a1e); a1o = fmaf(h1a.y, wo0, a1o);
            a0e = fmaf(h0a.z, we1, a0e); a0o = fmaf(h0a.w, wo1, a0o);
            a1e = fmaf(h1a.z, we1, a1e); a1o = fmaf(h1a.w, wo1, a1o);
            a0e = fmaf(h0b.x, we2, a0e); a0o = fmaf(h0b.y, wo2, a0o);
            a1e = fmaf(h1b.x, we2, a1e); a1o = fmaf(h1b.y, wo2, a1o);
            a0e = fmaf(h0b.z, we3, a0e); a0o = fmaf(h0b.w, wo3, a0o);
            a1e = fmaf(h1b.z, we3, a1e); a1o = fmaf(h1b.w, wo3, a1o);
        }
        *(float2*)&G2[tid][0] = make_float2(a0e + a0o, a1e + a1o);
        __syncthreads();
        if (tid < 2 * U) {
            float gi = G2[uu][ur], gj = G2[U + uu][ur];
            float gf = G2[2 * U + uu][ur], go = G2[3 * U + uu][ur];
            c_state = c_state * sig_(gf + 1.0f) + sig_(gi) * tanh_(gj);
            h32[ur][uu] = tanh_(c_state) * sig_(go);
        }
        __syncthreads();
    }
    if (tid < 2 * NC) {
        const int r = tid >> 7, n = tid & (NC - 1);
        float sum = bd[n];
        #pragma unroll 4
        for (int k = 0; k < U; ++k)
            sum = fmaf(h32[r][k], Wd[k * NC + n], sum);
        out[(r0 + r) * NC + n] = sum;
    }
}

extern "C" void kernel_launch(void* const* d_in, const int* in_sizes, int n_in,
                              void* d_out, int out_size, void* d_ws, size_t ws_size,
                              hipStream_t stream) {
    const int*   tokens = (const int*)d_in[0];
    const float* Wx     = (const float*)d_in[1];
    const float* Wh     = (const float*)d_in[2];
    const float* bias   = (const float*)d_in[3];
    const float* Wd     = (const float*)d_in[4];
    const float* bd     = (const float*)d_in[5];
    float*       out    = (float*)d_out;

    if (ws_size >= (size_t)WS_NEED) {
        uint4*  Wp  = (uint4*)((char*)d_ws + WP_OFF);
        float4* Wxp = (float4*)((char*)d_ws + WXP_OFF);
        pack_wh<<<128, 256, 0, stream>>>(Wh, Wp);
        pack_wx<<<128, 256, 0, stream>>>(Wx, bias, Wxp);
        lstm_reg16<<<512 / BCR, THREADS, 0, stream>>>(tokens, Wp, Wxp, Wd, bd, out);
    } else {
        uint4* Whb = (uint4*)d_ws;
        pack_kq<<<128, 256, 0, stream>>>(Wh, Whb);
        lstm_stream<<<256, 1024, 0, stream>>>(tokens, Wx, Whb, bias, Wd, bd, out);
    }
}

// Round 15
// 4399.195 us; speedup vs baseline: 1.0423x; 1.0423x over previous
//
#include <hip/hip_runtime.h>

// LSTM char-RNN scan: B=512, SEQ=1024, UNITS=256, NUM_CHARS=128. fp32 in/out.
// Round 14: 64-CU variant. r13's "full W residency" is impossible at 16
// waves/WG (128-reg cap); at 8 waves/WG the cap is 256 regs/wave, so:
//   - 64 WGs x 8 batch rows (BCR=8), 512 threads (8 waves), ~64 CUs active
//     (2x round 11's 32).
//   - wave wv owns unit blocks {wv, 8+wv}: all 8 of its nt tiles split
//     5 REG (160 regs) + 2 LDS (16 slots=128 KB total) + 1 STREAM
//     (64 KB/step/CU from L2 - half of r11).
//   - M-tile half-used (8 real rows of 16): wasted MFMA FLOPs, but MFMA is
//     ~15% of the cycle budget - CU doubling dominates.
//   - r11's proven step skeleton: 2 barriers, LDS token window, 1-deep
//     stream prefetch, inline Wxp gather (hoisting proven neutral in r12).
// Numerics frozen: W_h bf16 RNE, h bf16 RNE, c/gates fp32 (absmax 4.8828e-4).
// Risk: ~250 live regs; FETCH_SIZE GB-scale would signal spill (then trim to
// 4 REG tiles next round).

#define U       256
#define SEQ     1024
#define NC      128
#define GDIM    1024
#define BCR     8          // batch rows per WG
#define THREADS 512        // 8 waves

typedef short bf16x8 __attribute__((ext_vector_type(8)));
typedef float f32x4  __attribute__((ext_vector_type(4)));

#define WP_OFF   0                        // 512 KB packed W_h
#define WXP_OFF  (512*1024)               // 512 KB packed Wx+bias
#define WS_NEED  (1024*1024)

__device__ __forceinline__ float sig_(float x)  { return 1.0f / (1.0f + __expf(-x)); }
__device__ __forceinline__ float tanh_(float x) { return 1.0f - 2.0f / (__expf(2.0f * x) + 1.0f); }
__device__ __forceinline__ unsigned rne16(float f) {
    union { float f; unsigned u; } v; v.f = f;
    return (v.u + 0x7FFFu + ((v.u >> 16) & 1u)) >> 16;
}
__device__ __forceinline__ float u2f(unsigned u) {
    union { unsigned u; float f; } v; v.u = u; return v.f;
}

// ---- pack W_h into MFMA B-frag order (validated rounds 5-13) ----
// Wp[(nt*8+kt)*64 + lane]: col = nt*16+(lane&15); k = kt*32+(lane>>4)*8 + j,
// dword d packs (k=2d lo, k=2d+1 hi).
__global__ __launch_bounds__(256)
void pack_wh(const float* __restrict__ Wh, uint4* __restrict__ Wp) {
    int i    = blockIdx.x * 256 + threadIdx.x;   // [0, 32768)
    int lane = i & 63;
    int kt   = (i >> 6) & 7;
    int nt   = i >> 9;
    int col  = nt * 16 + (lane & 15);
    int k0   = kt * 32 + ((lane >> 4) * 8);
    const float* base = Wh + (size_t)k0 * GDIM + col;
    unsigned p0 = rne16(base[0 * GDIM]) | (rne16(base[1 * GDIM]) << 16);
    unsigned p1 = rne16(base[2 * GDIM]) | (rne16(base[3 * GDIM]) << 16);
    unsigned p2 = rne16(base[4 * GDIM]) | (rne16(base[5 * GDIM]) << 16);
    unsigned p3 = rne16(base[6 * GDIM]) | (rne16(base[7 * GDIM]) << 16);
    Wp[i] = make_uint4(p0, p1, p2, p3);
}

// ---- pack Wx + bias (+forget_bias) into float4 per (x, unit) ----
__global__ __launch_bounds__(256)
void pack_wx(const float* __restrict__ Wx, const float* __restrict__ bias,
             float4* __restrict__ Wxp) {
    int i = blockIdx.x * 256 + threadIdx.x;      // [0, 32768)
    int x = i >> 8, u = i & 255;
    const float* r = Wx + (size_t)x * GDIM;
    Wxp[i] = make_float4(r[u]       + bias[u],
                         r[256 + u] + bias[256 + u],
                         r[512 + u] + bias[512 + u] + 1.0f,   // forget_bias
                         r[768 + u] + bias[768 + u]);
}

__global__ __launch_bounds__(THREADS, 2)
void lstm_w64(const int* __restrict__ tokens,
              const uint4* __restrict__ Wp,     // packed W_h (ws)
              const float4* __restrict__ Wxp,   // packed Wx+b (ws)
              const float* __restrict__ Wd,     // [256,128]
              const float* __restrict__ bd,     // [128]
              float* __restrict__ out)          // [512,128]
{
    __shared__ uint4 LW[16][8][64];   // 128 KB  W in LDS (2 nt per wave)
    __shared__ short AH[8][64][8];    // 8 KB    h bf16, MFMA-A swizzled
    __shared__ int   tokw[64][8];     // 2 KB    64-step token window

    const int tid  = threadIdx.x;
    const int wv   = tid >> 6;        // wave 0..7
    const int lane = tid & 63;
    const int m    = lane & 15;
    const int quad = lane >> 4;
    const int r0   = blockIdx.x * BCR;

    // wave wv owns unit blocks {wv, 8+wv} (32 units), all 4 gates:
    // nt set = {wv, 8+wv, 16+wv, 24+wv, 32+wv, 40+wv, 48+wv, 56+wv}.
    // REG: first 5.  LDS: {40+wv, 48+wv}.  STREAM: {56+wv}.
    bf16x8 WR[5][8];                  // 160 regs
    #pragma unroll
    for (int jj = 0; jj < 5; ++jj)
        #pragma unroll
        for (int kt = 0; kt < 8; ++kt) {
            union { uint4 u; bf16x8 v; } c;
            c.u = Wp[((size_t)((wv + 8 * jj) * 8 + kt)) * 64 + lane];
            WR[jj][kt] = c.v;
        }
    const int slA = 2 * wv;
    #pragma unroll
    for (int kt = 0; kt < 8; ++kt) {
        LW[slA][kt][lane]     = Wp[((size_t)((40 + wv) * 8 + kt)) * 64 + lane];
        LW[slA + 1][kt][lane] = Wp[((size_t)((48 + wv) * 8 + kt)) * 64 + lane];
    }
    for (int i = tid; i < 2048; i += THREADS)    // zero A plane (as ints)
        ((int*)AH)[i] = 0;

    // update-phase constants: lane (quad<2) updates rows quad*4..quad*4+3 of
    // units u0 = wv*16+m and u1 = (8+wv)*16+m.
    float cst[2][4] = {{0.f,0.f,0.f,0.f},{0.f,0.f,0.f,0.f}};
    const int u0 = wv * 16 + m;
    const int u1 = (8 + wv) * 16 + m;
    const int kt0 = u0 >> 5, qa0 = (u0 >> 3) & 3, j0 = u0 & 7;
    const int kt1 = u1 >> 5, qa1 = (u1 >> 3) & 3, j1 = u1 & 7;
    const uint4* sp = Wp + ((size_t)(56 + wv) * 8) * 64 + lane;

    __syncthreads();

    for (int t = 0; t < SEQ; ++t) {
        if ((t & 63) == 0) {           // refresh token window
            tokw[tid >> 3][tid & 7] =
                tokens[(size_t)(r0 + (tid & 7)) * SEQ + t + (tid >> 3)];
            __syncthreads();
        }

        // ---- MFMA phase: 8 acc x 8 kt ----
        // acc: [0]=iA [1]=iB [2]=jA [3]=jB [4]=fA [5]=fB(LDS) [6]=oA(LDS)
        //      [7]=oB(stream)
        f32x4 acc[8];
        #pragma unroll
        for (int j = 0; j < 8; ++j) acc[j] = (f32x4){0.f, 0.f, 0.f, 0.f};

        uint4 s = sp[0];
        #pragma unroll
        for (int kt = 0; kt < 8; ++kt) {
            bf16x8 ah = *(const bf16x8*)&AH[kt][lane][0];
            uint4 n;
            if (kt < 7) n = sp[(kt + 1) * 64];
            union { uint4 u; bf16x8 v; } l0, l1, b;
            l0.u = LW[slA][kt][lane];
            l1.u = LW[slA + 1][kt][lane];
            b.u  = s;
            acc[0] = __builtin_amdgcn_mfma_f32_16x16x32_bf16(ah, WR[0][kt], acc[0], 0, 0, 0);
            acc[1] = __builtin_amdgcn_mfma_f32_16x16x32_bf16(ah, WR[1][kt], acc[1], 0, 0, 0);
            acc[2] = __builtin_amdgcn_mfma_f32_16x16x32_bf16(ah, WR[2][kt], acc[2], 0, 0, 0);
            acc[3] = __builtin_amdgcn_mfma_f32_16x16x32_bf16(ah, WR[3][kt], acc[3], 0, 0, 0);
            acc[4] = __builtin_amdgcn_mfma_f32_16x16x32_bf16(ah, WR[4][kt], acc[4], 0, 0, 0);
            acc[5] = __builtin_amdgcn_mfma_f32_16x16x32_bf16(ah, l0.v, acc[5], 0, 0, 0);
            acc[6] = __builtin_amdgcn_mfma_f32_16x16x32_bf16(ah, l1.v, acc[6], 0, 0, 0);
            acc[7] = __builtin_amdgcn_mfma_f32_16x16x32_bf16(ah, b.v, acc[7], 0, 0, 0);
            s = n;
        }

        // ---- in-register LSTM update (rows 0-7 live in quads 0,1) ----
        unsigned hh0[4], hh1[4];
        if (quad < 2) {
            #pragma unroll
            for (int ri = 0; ri < 4; ++ri) {
                const int x = tokw[t & 63][quad * 4 + ri];
                // unit block A: gates i=acc[0], j=acc[2], f=acc[4], o=acc[6]
                {
                    float4 wx = Wxp[(size_t)x * 256 + u0];
                    float gi = acc[0][ri] + wx.x;
                    float gj = acc[2][ri] + wx.y;
                    float gf = acc[4][ri] + wx.z;    // forget_bias folded
                    float go = acc[6][ri] + wx.w;
                    float c  = cst[0][ri];
                    c = c * sig_(gf) + sig_(gi) * tanh_(gj);
                    cst[0][ri] = c;
                    hh0[ri] = rne16(tanh_(c) * sig_(go));
                }
                // unit block B: gates i=acc[1], j=acc[3], f=acc[5], o=acc[7]
                {
                    float4 wx = Wxp[(size_t)x * 256 + u1];
                    float gi = acc[1][ri] + wx.x;
                    float gj = acc[3][ri] + wx.y;
                    float gf = acc[5][ri] + wx.z;
                    float go = acc[7][ri] + wx.w;
                    float c  = cst[1][ri];
                    c = c * sig_(gf) + sig_(gi) * tanh_(gj);
                    cst[1][ri] = c;
                    hh1[ri] = rne16(tanh_(c) * sig_(go));
                }
            }
        }
        __syncthreads();       // all A-reads of this step complete

        if (quad < 2) {
            #pragma unroll
            for (int ri = 0; ri < 4; ++ri) {
                const int row = quad * 4 + ri;
                AH[kt0][qa0 * 16 + row][j0] = (short)hh0[ri];
                AH[kt1][qa1 * 16 + row][j1] = (short)hh1[ri];
            }
        }
        __syncthreads();       // new h visible
    }

    // ---- final dense (h is bf16; 8 rows x 128 cols) ----
    for (int o = tid; o < BCR * NC; o += THREADS) {
        const int r = o >> 7;
        const int n = o & (NC - 1);
        float sum = bd[n];
        #pragma unroll 4
        for (int k = 0; k < U; ++k) {
            float hk = u2f(((unsigned)(unsigned short)
                            AH[k >> 5][((k >> 3) & 3) * 16 + r][k & 7]) << 16);
            sum = fmaf(hk, Wd[k * NC + n], sum);
        }
        out[(size_t)(r0 + r) * NC + n] = sum;
    }
}

// ================= fallback: round-5 streaming kernel (proven 7.6 ms) =========
__global__ __launch_bounds__(256)
void pack_kq(const float* __restrict__ Wh, uint4* __restrict__ Whb) {
    int idx = blockIdx.x * 256 + threadIdx.x;
    int kq  = idx >> 10;
    int c   = idx & 1023;
    const float* base = Wh + (size_t)(kq * 8) * GDIM + c;
    unsigned p0 = rne16(base[0 * GDIM]) | (rne16(base[1 * GDIM]) << 16);
    unsigned p1 = rne16(base[2 * GDIM]) | (rne16(base[3 * GDIM]) << 16);
    unsigned p2 = rne16(base[4 * GDIM]) | (rne16(base[5 * GDIM]) << 16);
    unsigned p3 = rne16(base[6 * GDIM]) | (rne16(base[7 * GDIM]) << 16);
    Whb[idx] = make_uint4(p0, p1, p2, p3);
}

__global__ __launch_bounds__(1024, 4)
void lstm_stream(const int* __restrict__ tokens, const float* __restrict__ Wx,
                 const uint4* __restrict__ Whb, const float* __restrict__ bias,
                 const float* __restrict__ Wd, const float* __restrict__ bd,
                 float* __restrict__ out)
{
    __shared__ float h32[2][U];
    __shared__ float G2[GDIM][2];
    __shared__ int   tok[2][SEQ];
    const int tid = threadIdx.x;
    const int r0  = blockIdx.x * 2;
    for (int i = tid; i < 2 * SEQ; i += 1024)
        ((int*)tok)[i] = tokens[r0 * SEQ + i];
    if (tid < 2 * U) ((float*)h32)[tid] = 0.0f;
    const float b_c = bias[tid];
    float c_state = 0.0f;
    const int ur = tid >> 8, uu = tid & 255;
    __syncthreads();
    const uint4* wp = Whb + tid;
    for (int t = 0; t < SEQ; ++t) {
        const int x0 = tok[0][t], x1 = tok[1][t];
        float a0e = Wx[x0 * GDIM + tid] + b_c;
        float a1e = Wx[x1 * GDIM + tid] + b_c;
        float a0o = 0.f, a1o = 0.f;
        #pragma unroll 4
        for (int kq = 0; kq < 32; ++kq) {
            float4 h0a = *(const float4*)&h32[0][kq * 8];
            float4 h0b = *(const float4*)&h32[0][kq * 8 + 4];
            float4 h1a = *(const float4*)&h32[1][kq * 8];
            float4 h1b = *(const float4*)&h32[1][kq * 8 + 4];
            uint4 wv2 = wp[kq << 10];
            float we0 = u2f(wv2.x << 16), wo0 = u2f(wv2.x & 0xffff0000u);
            float we1 = u2f(wv2.y << 16), wo1 = u2f(wv2.y & 0xffff0000u);
            float we2 = u2f(wv2.z << 16), wo2 = u2f(wv2.z & 0xffff0000u);
            float we3 = u2f(wv2.w << 16), wo3 = u2f(wv2.w & 0xffff0000u);
            a0e = fmaf(h0a.x, we0, a0e); a0o = fmaf(h0a.y, wo0, a0o);
            a1e = fmaf(h1a.x, we0, a1e); a1o = fmaf(h1a.y, wo0, a1o);
            a0e = fmaf(h0a.z, we1, a0e); a0o = fmaf(h0a.w, wo1, a0o);
            a1e = fmaf(h1a.z, we1, a1e); a1o = fmaf(h1a.w, wo1, a1o);
            a0e = fmaf(h0b.x, we2, a0e); a0o = fmaf(h0b.y, wo2, a0o);
            a1e = fmaf(h1b.x, we2, a1e); a1o = fmaf(h1b.y, wo2, a1o);
            a0e = fmaf(h0b.z, we3, a0e); a0o = fmaf(h0b.w, wo3, a0o);
            a1e = fmaf(h1b.z, we3, a1e); a1o = fmaf(h1b.w, wo3, a1o);
        }
        *(float2*)&G2[tid][0] = make_float2(a0e + a0o, a1e + a1o);
        __syncthreads();
        if (tid < 2 * U) {
            float gi = G2[uu][ur], gj = G2[U + uu][ur];
            float gf = G2[2 * U + uu][ur], go = G2[3 * U + uu][ur];
            c_state = c_state * sig_(gf + 1.0f) + sig_(gi) * tanh_(gj);
            h32[ur][uu] = tanh_(c_state) * sig_(go);
        }
        __syncthreads();
    }
    if (tid < 2 * NC) {
        const int r = tid >> 7, n = tid & (NC - 1);
        float sum = bd[n];
        #pragma unroll 4
        for (int k = 0; k < U; ++k)
            sum = fmaf(h32[r][k], Wd[k * NC + n], sum);
        out[(r0 + r) * NC + n] = sum;
    }
}

extern "C" void kernel_launch(void* const* d_in, const int* in_sizes, int n_in,
                              void* d_out, int out_size, void* d_ws, size_t ws_size,
                              hipStream_t stream) {
    const int*   tokens = (const int*)d_in[0];
    const float* Wx     = (const float*)d_in[1];
    const float* Wh     = (const float*)d_in[2];
    const float* bias   = (const float*)d_in[3];
    const float* Wd     = (const float*)d_in[4];
    const float* bd     = (const float*)d_in[5];
    float*       out    = (float*)d_out;

    if (ws_size >= (size_t)WS_NEED) {
        uint4*  Wp  = (uint4*)((char*)d_ws + WP_OFF);
        float4* Wxp = (float4*)((char*)d_ws + WXP_OFF);
        pack_wh<<<128, 256, 0, stream>>>(Wh, Wp);
        pack_wx<<<128, 256, 0, stream>>>(Wx, bias, Wxp);
        lstm_w64<<<512 / BCR, THREADS, 0, stream>>>(tokens, Wp, Wxp, Wd, bd, out);
    } else {
        uint4* Whb = (uint4*)d_ws;
        pack_kq<<<128, 256, 0, stream>>>(Wh, Whb);
        lstm_stream<<<256, 1024, 0, stream>>>(tokens, Wx, Whb, bias, Wd, bd, out);
    }
}